// Round 1
// baseline (1218.071 us; speedup 1.0000x reference)
//
#include <hip/hip_runtime.h>
#include <hip/hip_bf16.h>
#include <math.h>

// Problem constants (from reference)
#define NN 100000
#define EE 1600000
#define FIN 20
#define HH 128
#define NB1 391          // ceil(NN/256) scan blocks
#define GNB 256          // graphnorm partial blocks

// ---------------------------------------------------------------------------
// CSR build
// ---------------------------------------------------------------------------
__global__ void k_hist(const int* __restrict__ dst, int* __restrict__ deg) {
    int e = blockIdx.x * 256 + threadIdx.x;
    if (e < EE) atomicAdd(&deg[dst[e]], 1);
}

__global__ void k_scan1(const int* __restrict__ deg, int* __restrict__ incl,
                        int* __restrict__ bsum) {
    __shared__ int sh[256];
    int i = blockIdx.x * 256 + threadIdx.x;
    int v = (i < NN) ? deg[i] : 0;
    sh[threadIdx.x] = v;
    __syncthreads();
    for (int off = 1; off < 256; off <<= 1) {
        int add = (threadIdx.x >= off) ? sh[threadIdx.x - off] : 0;
        __syncthreads();
        sh[threadIdx.x] += add;
        __syncthreads();
    }
    if (i < NN) incl[i] = sh[threadIdx.x];
    if (threadIdx.x == 255) bsum[blockIdx.x] = sh[255];
}

__global__ void k_scan2(int* __restrict__ bsum) {
    __shared__ int sh[512];
    int t = threadIdx.x;
    sh[t] = (t < NB1) ? bsum[t] : 0;
    __syncthreads();
    for (int off = 1; off < 512; off <<= 1) {
        int add = (t >= off) ? sh[t - off] : 0;
        __syncthreads();
        sh[t] += add;
        __syncthreads();
    }
    if (t < NB1) bsum[t] = sh[t];
}

__global__ void k_scan3(const int* __restrict__ deg, const int* __restrict__ incl,
                        const int* __restrict__ bsum, int* __restrict__ row_start,
                        float* __restrict__ invdeg) {
    int i = blockIdx.x * 256 + threadIdx.x;
    if (i >= NN) return;
    int v = incl[i] + (blockIdx.x ? bsum[blockIdx.x - 1] : 0);
    int d = deg[i];
    row_start[i] = v - d;
    invdeg[i] = 1.0f / fmaxf((float)d, 1.0f);
}

__global__ void k_scatter(const int* __restrict__ src, const int* __restrict__ dst,
                          const int* __restrict__ row_start, int* __restrict__ cnt,
                          int* __restrict__ col) {
    int e = blockIdx.x * 256 + threadIdx.x;
    if (e >= EE) return;
    int d = dst[e];
    int pos = row_start[d] + atomicAdd(&cnt[d], 1);
    col[pos] = src[e];
}

// ---------------------------------------------------------------------------
// Layer 0: aggregate 20-wide x, then fused dual GEMM (K=20, weights in regs)
// ---------------------------------------------------------------------------
__global__ void k_agg0(const float* __restrict__ x, const int* __restrict__ rs,
                       const int* __restrict__ deg, const float* __restrict__ inv,
                       const int* __restrict__ col, float* __restrict__ agg0) {
    int g = threadIdx.x >> 5;
    int l = threadIdx.x & 31;
    int n = blockIdx.x * 4 + g;
    if (n >= NN || l >= FIN) return;
    int s = rs[n], d = deg[n];
    float acc = 0.0f;
    int j = 0;
    for (; j + 1 < d; j += 2) {
        int c0 = col[s + j], c1 = col[s + j + 1];
        acc += x[c0 * FIN + l] + x[c1 * FIN + l];
    }
    if (j < d) acc += x[col[s + j] * FIN + l];
    agg0[n * FIN + l] = acc * inv[n];
}

__global__ __launch_bounds__(128) void k_l0(const float* __restrict__ agg0,
        const float* __restrict__ x, const float* __restrict__ Wl,
        const float* __restrict__ bl, const float* __restrict__ Wr,
        float* __restrict__ y) {
    int c = threadIdx.x;  // output channel 0..127
    float wl[FIN], wr[FIN];
    #pragma unroll
    for (int k = 0; k < FIN; ++k) wl[k] = Wl[c * FIN + k];
    #pragma unroll
    for (int k = 0; k < FIN; ++k) wr[k] = Wr[c * FIN + k];
    float bc = bl[c];
    for (int n = blockIdx.x; n < NN; n += gridDim.x) {
        const float* ar = agg0 + (size_t)n * FIN;
        const float* xr = x + (size_t)n * FIN;
        float acc = bc;
        #pragma unroll
        for (int k = 0; k < FIN; ++k) acc = fmaf(ar[k], wl[k], acc);
        #pragma unroll
        for (int k = 0; k < FIN; ++k) acc = fmaf(xr[k], wr[k], acc);
        y[(size_t)n * HH + c] = acc;
    }
}

// ---------------------------------------------------------------------------
// Wide-layer aggregation: one node per 128-thread block, coalesced row reads
// ---------------------------------------------------------------------------
__global__ __launch_bounds__(128) void k_agg(const float* __restrict__ h,
        const int* __restrict__ rs, const int* __restrict__ deg,
        const float* __restrict__ inv, const int* __restrict__ col,
        float* __restrict__ agg) {
    int n = blockIdx.x;
    int t = threadIdx.x;
    int s = rs[n], d = deg[n];
    float acc = 0.0f;
    int j = 0;
    for (; j + 3 < d; j += 4) {
        int c0 = col[s + j], c1 = col[s + j + 1], c2 = col[s + j + 2], c3 = col[s + j + 3];
        float v0 = h[(size_t)c0 * HH + t];
        float v1 = h[(size_t)c1 * HH + t];
        float v2 = h[(size_t)c2 * HH + t];
        float v3 = h[(size_t)c3 * HH + t];
        acc += v0 + v1 + v2 + v3;
    }
    for (; j < d; ++j) acc += h[(size_t)col[s + j] * HH + t];
    agg[(size_t)n * HH + t] = acc * inv[n];
}

// ---------------------------------------------------------------------------
// Weight pack: Wt[k][c], k in [0,256): k<128 -> Wl[c][k], else Wr[c][k-128]
// ---------------------------------------------------------------------------
__global__ void k_pack(const float* __restrict__ Wl, const float* __restrict__ Wr,
                       float* __restrict__ Wt) {
    int id = blockIdx.x * 256 + threadIdx.x;   // 32768 total
    int k = id >> 7, c = id & 127;
    Wt[id] = (k < HH) ? Wl[c * HH + k] : Wr[c * HH + (k - HH)];
}

// ---------------------------------------------------------------------------
// Main GEMM: y[m][c] = sum_k [agg|h][m][k] * Wt[k][c] + bias[c]
// Tile: 128 nodes x 128 out, BK=32, 256 threads, 8x8 micro-tile.
// y may alias agg (block reads only its own rows, all before epilogue).
// ---------------------------------------------------------------------------
__global__ __launch_bounds__(256, 4) void k_gemm(const float* agg,
        const float* __restrict__ h, const float* __restrict__ Wt,
        const float* __restrict__ bias, float* y) {
    __shared__ float As[128 * 33];
    __shared__ float Bs[32 * 128];
    const int tid = threadIdx.x;
    const int tm = tid & 15, tn = tid >> 4;
    const int m0 = blockIdx.x * 128;
    float acc[8][8];
    #pragma unroll
    for (int i = 0; i < 8; ++i)
        #pragma unroll
        for (int j = 0; j < 8; ++j) acc[i][j] = 0.0f;

    for (int chunk = 0; chunk < 8; ++chunk) {
        const float* A = (chunk < 4) ? agg : h;
        const int kb = (chunk & 3) * 32;
        // stage A: 128 rows x 32 cols
        #pragma unroll
        for (int jj = 0; jj < 4; ++jj) {
            int p = tid + jj * 256;
            int r = p >> 3;
            int c4 = (p & 7) << 2;
            int gr = m0 + r;
            float4 v = make_float4(0.f, 0.f, 0.f, 0.f);
            if (gr < NN) v = *(const float4*)(A + (size_t)gr * HH + kb + c4);
            As[r * 33 + c4 + 0] = v.x;
            As[r * 33 + c4 + 1] = v.y;
            As[r * 33 + c4 + 2] = v.z;
            As[r * 33 + c4 + 3] = v.w;
        }
        // stage B: 32 x 128 k-major, fully coalesced
        #pragma unroll
        for (int jj = 0; jj < 4; ++jj) {
            int p = tid + jj * 256;
            ((float4*)Bs)[p] = ((const float4*)Wt)[chunk * (32 * 128 / 4) + p];
        }
        __syncthreads();
        #pragma unroll 8
        for (int k = 0; k < 32; ++k) {
            float a[8], b[8];
            #pragma unroll
            for (int i = 0; i < 8; ++i) a[i] = As[(tm + 16 * i) * 33 + k];
            float4 b0 = *(const float4*)&Bs[k * 128 + tn * 8];
            float4 b1 = *(const float4*)&Bs[k * 128 + tn * 8 + 4];
            b[0] = b0.x; b[1] = b0.y; b[2] = b0.z; b[3] = b0.w;
            b[4] = b1.x; b[5] = b1.y; b[6] = b1.z; b[7] = b1.w;
            #pragma unroll
            for (int i = 0; i < 8; ++i)
                #pragma unroll
                for (int j = 0; j < 8; ++j) acc[i][j] = fmaf(a[i], b[j], acc[i][j]);
        }
        __syncthreads();
    }
    float bsv[8];
    #pragma unroll
    for (int j = 0; j < 8; ++j) bsv[j] = bias[tn * 8 + j];
    #pragma unroll
    for (int i = 0; i < 8; ++i) {
        int gr = m0 + tm + 16 * i;
        if (gr < NN) {
            float4 o0 = make_float4(acc[i][0] + bsv[0], acc[i][1] + bsv[1],
                                    acc[i][2] + bsv[2], acc[i][3] + bsv[3]);
            float4 o1 = make_float4(acc[i][4] + bsv[4], acc[i][5] + bsv[5],
                                    acc[i][6] + bsv[6], acc[i][7] + bsv[7]);
            *(float4*)(y + (size_t)gr * HH + tn * 8) = o0;
            *(float4*)(y + (size_t)gr * HH + tn * 8 + 4) = o1;
        }
    }
}

// ---------------------------------------------------------------------------
// GraphNorm: two-stage channel reduction, then fused affine+GELU apply
// ---------------------------------------------------------------------------
__global__ __launch_bounds__(256) void k_gn_part(const float* __restrict__ y,
        float* __restrict__ ps, float* __restrict__ pq) {
    int c = threadIdx.x & 127, half = threadIdx.x >> 7;
    float s = 0.0f, q = 0.0f;
    for (int n = blockIdx.x * 2 + half; n < NN; n += gridDim.x * 2) {
        float v = y[(size_t)n * HH + c];
        s += v;
        q += v * v;
    }
    __shared__ float sh[256], qh[256];
    sh[threadIdx.x] = s;
    qh[threadIdx.x] = q;
    __syncthreads();
    if (threadIdx.x < 128) {
        ps[blockIdx.x * 128 + c] = sh[c] + sh[c + 128];
        pq[blockIdx.x * 128 + c] = qh[c] + qh[c + 128];
    }
}

__global__ void k_gn_final(const float* __restrict__ ps, const float* __restrict__ pq,
                           const float* __restrict__ gw, const float* __restrict__ gb,
                           const float* __restrict__ ga, float* __restrict__ cA,
                           float* __restrict__ cB) {
    int c = threadIdx.x;  // 128 threads
    double s = 0.0, q = 0.0;
    for (int b = 0; b < GNB; ++b) {
        s += (double)ps[b * 128 + c];
        q += (double)pq[b * 128 + c];
    }
    float mean = (float)(s / (double)NN);
    float msq  = (float)(q / (double)NN);
    float a = ga[c];
    float var = msq - mean * mean * a * (2.0f - a);
    float rstd = rsqrtf(var + 1e-5f);
    float A = gw[c] * rstd;
    cA[c] = A;
    cB[c] = gb[c] - a * mean * A;
}

__device__ __forceinline__ float gelu_exact(float z) {
    return 0.5f * z * (1.0f + erff(z * 0.70710678118654752f));
}

__global__ __launch_bounds__(256) void k_gn_apply(const float* __restrict__ y,
        const float* __restrict__ cA, const float* __restrict__ cB,
        float* __restrict__ hout) {
    int i = blockIdx.x * 256 + threadIdx.x;  // float4 index
    if (i >= NN * (HH / 4)) return;
    int q = i & 31;
    float4 v = ((const float4*)y)[i];
    float4 A = ((const float4*)cA)[q];
    float4 B = ((const float4*)cB)[q];
    float4 o;
    o.x = gelu_exact(v.x * A.x + B.x);
    o.y = gelu_exact(v.y * A.y + B.y);
    o.z = gelu_exact(v.z * A.z + B.z);
    o.w = gelu_exact(v.w * A.w + B.w);
    ((float4*)hout)[i] = o;
}

// ---------------------------------------------------------------------------
// Fused MLP head: 128 -> 64 -> 32 -> 1, weights in LDS, 4 nodes per iter
// ---------------------------------------------------------------------------
__global__ __launch_bounds__(256) void k_head(const float* __restrict__ h,
        const float* __restrict__ W1, const float* __restrict__ b1,
        const float* __restrict__ W2, const float* __restrict__ b2,
        const float* __restrict__ W3, const float* __restrict__ b3,
        float* __restrict__ out) {
    __shared__ float W1s[64 * 129];
    __shared__ float W2s[32 * 65];
    __shared__ float W3s[32];
    __shared__ float b1s[64], b2s[32], b3s;
    __shared__ float hrow[4 * 128];
    __shared__ float z1[4 * 64];
    __shared__ float z2[4 * 32];
    int t = threadIdx.x;
    for (int i = t; i < 64 * 128; i += 256) W1s[(i >> 7) * 129 + (i & 127)] = W1[i];
    for (int i = t; i < 32 * 64; i += 256) W2s[(i >> 6) * 65 + (i & 63)] = W2[i];
    if (t < 32) W3s[t] = W3[t];
    if (t < 64) b1s[t] = b1[t];
    if (t >= 64 && t < 96) b2s[t - 64] = b2[t - 64];
    if (t == 96) b3s = b3[0];
    __syncthreads();
    for (int n0 = blockIdx.x * 4; n0 < NN; n0 += gridDim.x * 4) {
        for (int i = t; i < 512; i += 256) {
            int g = i >> 7, k = i & 127;
            int n = n0 + g;
            hrow[i] = (n < NN) ? h[(size_t)n * HH + k] : 0.0f;
        }
        __syncthreads();
        {
            int g = t >> 6, c = t & 63;
            float acc = b1s[c];
            #pragma unroll 8
            for (int k = 0; k < 128; ++k) acc = fmaf(hrow[g * 128 + k], W1s[c * 129 + k], acc);
            z1[g * 64 + c] = gelu_exact(acc);
        }
        __syncthreads();
        if (t < 128) {
            int g = t >> 5, c = t & 31;
            float acc = b2s[c];
            #pragma unroll 8
            for (int k = 0; k < 64; ++k) acc = fmaf(z1[g * 64 + k], W2s[c * 65 + k], acc);
            z2[g * 32 + c] = gelu_exact(acc);
        }
        __syncthreads();
        if (t < 4) {
            int n = n0 + t;
            if (n < NN) {
                float acc = b3s;
                #pragma unroll
                for (int k = 0; k < 32; ++k) acc = fmaf(z2[t * 32 + k], W3s[k], acc);
                out[n] = 1.0f / (1.0f + expf(-acc));
            }
        }
        __syncthreads();
    }
}

// ---------------------------------------------------------------------------
// Launch
// ---------------------------------------------------------------------------
extern "C" void kernel_launch(void* const* d_in, const int* in_sizes, int n_in,
                              void* d_out, int out_size, void* d_ws, size_t ws_size,
                              hipStream_t stream) {
    const float* x   = (const float*)d_in[0];
    const int*   ei  = (const int*)d_in[1];
    const float* Wl0 = (const float*)d_in[2];
    const float* bl0 = (const float*)d_in[3];
    const float* Wr0 = (const float*)d_in[4];
    const float* gw0 = (const float*)d_in[5];
    const float* gb0 = (const float*)d_in[6];
    const float* ga0 = (const float*)d_in[7];
    const float* Wl1 = (const float*)d_in[8];
    const float* bl1 = (const float*)d_in[9];
    const float* Wr1 = (const float*)d_in[10];
    const float* gw1 = (const float*)d_in[11];
    const float* gb1 = (const float*)d_in[12];
    const float* ga1 = (const float*)d_in[13];
    const float* Wl2 = (const float*)d_in[14];
    const float* bl2 = (const float*)d_in[15];
    const float* Wr2 = (const float*)d_in[16];
    const float* gw2 = (const float*)d_in[17];
    const float* gb2 = (const float*)d_in[18];
    const float* ga2 = (const float*)d_in[19];
    const float* hW1 = (const float*)d_in[20];
    const float* hb1 = (const float*)d_in[21];
    const float* hW2 = (const float*)d_in[22];
    const float* hb2 = (const float*)d_in[23];
    const float* hW3 = (const float*)d_in[24];
    const float* hb3 = (const float*)d_in[25];
    float* out = (float*)d_out;

    size_t off = 0;
    auto carve = [&](size_t bytes) -> void* {
        void* p = (void*)((char*)d_ws + off);
        off += (bytes + 255) & ~(size_t)255;
        return p;
    };
    int*   deg       = (int*)carve((size_t)2 * NN * sizeof(int));
    int*   cnt       = deg + NN;
    int*   incl      = (int*)carve((size_t)NN * 4);
    int*   row_start = (int*)carve((size_t)NN * 4);
    float* invdeg    = (float*)carve((size_t)NN * 4);
    int*   bsum      = (int*)carve(512 * 4);
    int*   colarr    = (int*)carve((size_t)EE * 4);
    float* Wt        = (float*)carve(256 * 128 * 4);
    float* ps        = (float*)carve(GNB * 128 * 4);
    float* pq        = (float*)carve(GNB * 128 * 4);
    float* coefA     = (float*)carve(128 * 4);
    float* coefB     = (float*)carve(128 * 4);
    float* agg0      = (float*)carve((size_t)NN * FIN * 4);
    float* bufA      = (float*)carve((size_t)NN * HH * 4);
    float* bufB      = (float*)carve((size_t)NN * HH * 4);
    if (off > ws_size) return;  // insufficient workspace

    const int* src = ei;
    const int* dst = ei + EE;

    // CSR build
    hipMemsetAsync(deg, 0, (size_t)2 * NN * sizeof(int), stream);
    k_hist<<<(EE + 255) / 256, 256, 0, stream>>>(dst, deg);
    k_scan1<<<NB1, 256, 0, stream>>>(deg, incl, bsum);
    k_scan2<<<1, 512, 0, stream>>>(bsum);
    k_scan3<<<NB1, 256, 0, stream>>>(deg, incl, bsum, row_start, invdeg);
    k_scatter<<<(EE + 255) / 256, 256, 0, stream>>>(src, dst, row_start, cnt, colarr);

    // Layer 0
    k_agg0<<<(NN + 3) / 4, 128, 0, stream>>>(x, row_start, deg, invdeg, colarr, agg0);
    k_l0<<<2048, 128, 0, stream>>>(agg0, x, Wl0, bl0, Wr0, bufB);
    k_gn_part<<<GNB, 256, 0, stream>>>(bufB, ps, pq);
    k_gn_final<<<1, 128, 0, stream>>>(ps, pq, gw0, gb0, ga0, coefA, coefB);
    k_gn_apply<<<(NN * (HH / 4) + 255) / 256, 256, 0, stream>>>(bufB, coefA, coefB, bufA);

    // Layers 1 and 2
    const float* WlL[2] = {Wl1, Wl2};
    const float* blL[2] = {bl1, bl2};
    const float* WrL[2] = {Wr1, Wr2};
    const float* gwL[2] = {gw1, gw2};
    const float* gbL[2] = {gb1, gb2};
    const float* gaL[2] = {ga1, ga2};
    for (int l = 0; l < 2; ++l) {
        k_pack<<<128, 256, 0, stream>>>(WlL[l], WrL[l], Wt);
        k_agg<<<NN, 128, 0, stream>>>(bufA, row_start, deg, invdeg, colarr, bufB);
        k_gemm<<<(NN + 127) / 128, 256, 0, stream>>>(bufB, bufA, Wt, blL[l], bufB);
        k_gn_part<<<GNB, 256, 0, stream>>>(bufB, ps, pq);
        k_gn_final<<<1, 128, 0, stream>>>(ps, pq, gwL[l], gbL[l], gaL[l], coefA, coefB);
        k_gn_apply<<<(NN * (HH / 4) + 255) / 256, 256, 0, stream>>>(bufB, coefA, coefB, bufA);
    }

    // Head MLP
    k_head<<<1024, 256, 0, stream>>>(bufA, hW1, hb1, hW2, hb2, hW3, hb3, out);
}

// Round 2
// 902.341 us; speedup vs baseline: 1.3499x; 1.3499x over previous
//
#include <hip/hip_runtime.h>
#include <hip/hip_bf16.h>
#include <math.h>

// Problem constants
#define NN 100000
#define EE 1600000
#define FIN 20
#define HH 128
#define NB1 391          // ceil(NN/256) scan blocks
#define GNB 256          // graphnorm partial blocks

typedef __attribute__((ext_vector_type(8))) short bf16x8;
typedef __attribute__((ext_vector_type(4))) float f32x4;

// bf16 helpers (RNE pack, cheap unpack)
__device__ __forceinline__ unsigned short f2b(float x) {
    unsigned int b = __float_as_uint(x);
    unsigned int r = b + 0x7fffu + ((b >> 16) & 1u);
    return (unsigned short)(r >> 16);
}
__device__ __forceinline__ float lof(unsigned int u) { return __uint_as_float(u << 16); }
__device__ __forceinline__ float hif(unsigned int u) { return __uint_as_float(u & 0xffff0000u); }

__device__ __forceinline__ float gelu_exact(float z) {
    return 0.5f * z * (1.0f + erff(z * 0.70710678118654752f));
}

// ---------------------------------------------------------------------------
// CSR build
// ---------------------------------------------------------------------------
__global__ void k_hist(const int* __restrict__ dst, int* __restrict__ deg) {
    int e = blockIdx.x * 256 + threadIdx.x;
    if (e < EE) atomicAdd(&deg[dst[e]], 1);
}

__global__ void k_scan1(const int* __restrict__ deg, int* __restrict__ incl,
                        int* __restrict__ bsum) {
    __shared__ int sh[256];
    int i = blockIdx.x * 256 + threadIdx.x;
    int v = (i < NN) ? deg[i] : 0;
    sh[threadIdx.x] = v;
    __syncthreads();
    for (int off = 1; off < 256; off <<= 1) {
        int add = (threadIdx.x >= off) ? sh[threadIdx.x - off] : 0;
        __syncthreads();
        sh[threadIdx.x] += add;
        __syncthreads();
    }
    if (i < NN) incl[i] = sh[threadIdx.x];
    if (threadIdx.x == 255) bsum[blockIdx.x] = sh[255];
}

__global__ void k_scan2(int* __restrict__ bsum) {
    __shared__ int sh[512];
    int t = threadIdx.x;
    sh[t] = (t < NB1) ? bsum[t] : 0;
    __syncthreads();
    for (int off = 1; off < 512; off <<= 1) {
        int add = (t >= off) ? sh[t - off] : 0;
        __syncthreads();
        sh[t] += add;
        __syncthreads();
    }
    if (t < NB1) bsum[t] = sh[t];
}

__global__ void k_scan3(const int* __restrict__ deg, const int* __restrict__ incl,
                        const int* __restrict__ bsum, int* __restrict__ row_start,
                        float* __restrict__ invdeg) {
    int i = blockIdx.x * 256 + threadIdx.x;
    if (i >= NN) return;
    int v = incl[i] + (blockIdx.x ? bsum[blockIdx.x - 1] : 0);
    int d = deg[i];
    row_start[i] = v - d;
    invdeg[i] = 1.0f / fmaxf((float)d, 1.0f);
}

__global__ void k_scatter(const int* __restrict__ src, const int* __restrict__ dst,
                          const int* __restrict__ row_start, int* __restrict__ cnt,
                          int* __restrict__ col) {
    int e = blockIdx.x * 256 + threadIdx.x;
    if (e >= EE) return;
    int d = dst[e];
    int pos = row_start[d] + atomicAdd(&cnt[d], 1);
    col[pos] = src[e];
}

// ---------------------------------------------------------------------------
// Layer 0 (fp32): aggregate 20-wide x, fused dual GEMM K=20 with regs
// ---------------------------------------------------------------------------
__global__ void k_agg0(const float* __restrict__ x, const int* __restrict__ rs,
                       const int* __restrict__ deg, const float* __restrict__ inv,
                       const int* __restrict__ col, float* __restrict__ agg0) {
    int g = threadIdx.x >> 5;
    int l = threadIdx.x & 31;
    int n = blockIdx.x * 4 + g;
    if (n >= NN || l >= FIN) return;
    int s = rs[n], d = deg[n];
    float acc = 0.0f;
    int j = 0;
    for (; j + 1 < d; j += 2) {
        int c0 = col[s + j], c1 = col[s + j + 1];
        acc += x[c0 * FIN + l] + x[c1 * FIN + l];
    }
    if (j < d) acc += x[col[s + j] * FIN + l];
    agg0[n * FIN + l] = acc * inv[n];
}

__global__ __launch_bounds__(128) void k_l0(const float* __restrict__ agg0,
        const float* __restrict__ x, const float* __restrict__ Wl,
        const float* __restrict__ bl, const float* __restrict__ Wr,
        float* __restrict__ y) {
    int c = threadIdx.x;
    float wl[FIN], wr[FIN];
    #pragma unroll
    for (int k = 0; k < FIN; ++k) wl[k] = Wl[c * FIN + k];
    #pragma unroll
    for (int k = 0; k < FIN; ++k) wr[k] = Wr[c * FIN + k];
    float bc = bl[c];
    for (int n = blockIdx.x; n < NN; n += gridDim.x) {
        const float* ar = agg0 + (size_t)n * FIN;
        const float* xr = x + (size_t)n * FIN;
        float acc = bc;
        #pragma unroll
        for (int k = 0; k < FIN; ++k) acc = fmaf(ar[k], wl[k], acc);
        #pragma unroll
        for (int k = 0; k < FIN; ++k) acc = fmaf(xr[k], wr[k], acc);
        y[(size_t)n * HH + c] = acc;
    }
}

// ---------------------------------------------------------------------------
// bf16 aggregation: 1 wave per node, lane = 2 channels, coalesced 256 B rows
// ---------------------------------------------------------------------------
__global__ __launch_bounds__(64) void k_aggb(const unsigned short* __restrict__ hB,
        const int* __restrict__ rs, const int* __restrict__ deg,
        const float* __restrict__ inv, const int* __restrict__ col,
        unsigned short* __restrict__ aggB) {
    int n = blockIdx.x;
    int t = threadIdx.x;
    int s = rs[n], d = deg[n];
    const unsigned int* h32 = (const unsigned int*)hB;
    float a0 = 0.0f, a1 = 0.0f;
    int j = 0;
    for (; j + 3 < d; j += 4) {
        int c0 = col[s + j], c1 = col[s + j + 1];
        int c2 = col[s + j + 2], c3 = col[s + j + 3];
        unsigned int u0 = h32[(size_t)c0 * 64 + t];
        unsigned int u1 = h32[(size_t)c1 * 64 + t];
        unsigned int u2 = h32[(size_t)c2 * 64 + t];
        unsigned int u3 = h32[(size_t)c3 * 64 + t];
        a0 += lof(u0) + lof(u1) + lof(u2) + lof(u3);
        a1 += hif(u0) + hif(u1) + hif(u2) + hif(u3);
    }
    for (; j < d; ++j) {
        unsigned int u = h32[(size_t)col[s + j] * 64 + t];
        a0 += lof(u);
        a1 += hif(u);
    }
    float iv = inv[n];
    unsigned int o = (unsigned int)f2b(a0 * iv) | ((unsigned int)f2b(a1 * iv) << 16);
    ((unsigned int*)aggB)[(size_t)n * 64 + t] = o;
}

// ---------------------------------------------------------------------------
// Weight / bias packing to bf16 (B stored c-major: B[c][k])
// ---------------------------------------------------------------------------
__global__ void k_pack_main(const float* __restrict__ Wl, const float* __restrict__ Wr,
                            unsigned short* __restrict__ Wt) {
    int id = blockIdx.x * 256 + threadIdx.x;   // 32768
    int c = id >> 8, k = id & 255;
    float v = (k < HH) ? Wl[c * HH + k] : Wr[c * HH + (k - HH)];
    Wt[id] = f2b(v);
}

__global__ void k_pack_h1(const float* __restrict__ W, unsigned short* __restrict__ Wt) {
    int id = blockIdx.x * 256 + threadIdx.x;   // 128*128
    int c = id >> 7, k = id & 127;
    Wt[id] = f2b((c < 64) ? W[c * 128 + k] : 0.0f);
}

__global__ void k_pack_h2(const float* __restrict__ W, unsigned short* __restrict__ Wt) {
    int id = blockIdx.x * 256 + threadIdx.x;   // 128*64
    int c = id >> 6, k = id & 63;
    Wt[id] = f2b((c < 32) ? W[c * 64 + k] : 0.0f);
}

__global__ void k_padbias(const float* __restrict__ src, int n, float* __restrict__ dst) {
    int t = threadIdx.x;  // 128
    dst[t] = (t < n) ? src[t] : 0.0f;
}

// ---------------------------------------------------------------------------
// Generic bf16 MFMA GEMM: out[m][c] = act( sum_k A[m][k]*B[c][k] + bias[c] )
// Tile 128m x 128c, K = kChunks*32; chunks < c0 read A0, else A1.
// B is c-major bf16 [128][ldb]. outF fp32 (stride 128) and/or outB bf16.
// ---------------------------------------------------------------------------
__global__ __launch_bounds__(256) void k_mm(const unsigned short* __restrict__ A0,
        const unsigned short* __restrict__ A1, int c0, int kChunks, int lda,
        const unsigned short* __restrict__ B, int ldb,
        const float* __restrict__ bias, float* outF, unsigned short* outB,
        int act, int M) {
    __shared__ __align__(16) unsigned short As[128 * 40];
    __shared__ __align__(16) unsigned short Bs[128 * 40];
    const int tid = threadIdx.x;
    const int m0 = blockIdx.x * 128;
    const int w = tid >> 6, lane = tid & 63;
    const int wr = w >> 1, wc = w & 1;
    const int m16 = lane & 15, q = lane >> 4;

    f32x4 acc[4][4];
    #pragma unroll
    for (int i = 0; i < 4; ++i)
        #pragma unroll
        for (int j = 0; j < 4; ++j) acc[i][j] = (f32x4){0.f, 0.f, 0.f, 0.f};

    for (int chunk = 0; chunk < kChunks; ++chunk) {
        const unsigned short* A = (chunk < c0) ? A0 : A1;
        const int kb = (chunk - ((chunk < c0) ? 0 : c0)) * 32;
        // stage A: 128 rows x 32 bf16 (64 B/row), 512 uint4 slots
        #pragma unroll
        for (int it = 0; it < 2; ++it) {
            int s = tid + it * 256;
            int r = s >> 2, p = s & 3;
            int gm = m0 + r;
            uint4 v = make_uint4(0u, 0u, 0u, 0u);
            if (gm < M) v = *(const uint4*)(A + (size_t)gm * lda + kb + p * 8);
            *(uint4*)&As[r * 40 + p * 8] = v;
        }
        // stage B: 128 c-rows x 32 bf16
        {
            const int kbB = chunk * 32;
            #pragma unroll
            for (int it = 0; it < 2; ++it) {
                int s = tid + it * 256;
                int r = s >> 2, p = s & 3;
                uint4 v = *(const uint4*)(B + (size_t)r * ldb + kbB + p * 8);
                *(uint4*)&Bs[r * 40 + p * 8] = v;
            }
        }
        __syncthreads();
        bf16x8 af[4], bf[4];
        #pragma unroll
        for (int i = 0; i < 4; ++i)
            af[i] = *(const bf16x8*)&As[(wr * 64 + i * 16 + m16) * 40 + q * 8];
        #pragma unroll
        for (int j = 0; j < 4; ++j)
            bf[j] = *(const bf16x8*)&Bs[(wc * 64 + j * 16 + m16) * 40 + q * 8];
        #pragma unroll
        for (int i = 0; i < 4; ++i)
            #pragma unroll
            for (int j = 0; j < 4; ++j)
                acc[i][j] = __builtin_amdgcn_mfma_f32_16x16x32_bf16(af[i], bf[j], acc[i][j], 0, 0, 0);
        __syncthreads();
    }

    // epilogue: D[row=q*4+r][col=m16] within each 16x16 tile
    #pragma unroll
    for (int i = 0; i < 4; ++i) {
        int mBase = m0 + wr * 64 + i * 16 + q * 4;
        #pragma unroll
        for (int j = 0; j < 4; ++j) {
            int cc = wc * 64 + j * 16 + m16;
            float bv = bias[cc];
            #pragma unroll
            for (int r = 0; r < 4; ++r) {
                int m = mBase + r;
                if (m < M) {
                    float v = acc[i][j][r] + bv;
                    if (act) v = gelu_exact(v);
                    if (outF) outF[(size_t)m * 128 + cc] = v;
                    if (outB) outB[(size_t)m * 128 + cc] = f2b(v);
                }
            }
        }
    }
}

// ---------------------------------------------------------------------------
// GraphNorm: partial sums, final coeffs, fused affine+GELU apply -> bf16
// ---------------------------------------------------------------------------
__global__ __launch_bounds__(256) void k_gn_part(const float* __restrict__ y,
        float* __restrict__ ps, float* __restrict__ pq) {
    int c = threadIdx.x & 127, half = threadIdx.x >> 7;
    float s = 0.0f, q = 0.0f;
    for (int n = blockIdx.x * 2 + half; n < NN; n += gridDim.x * 2) {
        float v = y[(size_t)n * HH + c];
        s += v;
        q += v * v;
    }
    __shared__ float sh[256], qh[256];
    sh[threadIdx.x] = s;
    qh[threadIdx.x] = q;
    __syncthreads();
    if (threadIdx.x < 128) {
        ps[blockIdx.x * 128 + c] = sh[c] + sh[c + 128];
        pq[blockIdx.x * 128 + c] = qh[c] + qh[c + 128];
    }
}

__global__ void k_gn_final(const float* __restrict__ ps, const float* __restrict__ pq,
                           const float* __restrict__ gw, const float* __restrict__ gb,
                           const float* __restrict__ ga, float* __restrict__ cA,
                           float* __restrict__ cB) {
    int c = threadIdx.x;  // 128
    double s = 0.0, q = 0.0;
    for (int b = 0; b < GNB; ++b) {
        s += (double)ps[b * 128 + c];
        q += (double)pq[b * 128 + c];
    }
    float mean = (float)(s / (double)NN);
    float msq  = (float)(q / (double)NN);
    float a = ga[c];
    float var = msq - mean * mean * a * (2.0f - a);
    float rstd = rsqrtf(var + 1e-5f);
    float A = gw[c] * rstd;
    cA[c] = A;
    cB[c] = gb[c] - a * mean * A;
}

__global__ __launch_bounds__(256) void k_gn_apply(const float* __restrict__ y,
        const float* __restrict__ cA, const float* __restrict__ cB,
        unsigned short* __restrict__ hB) {
    int i = blockIdx.x * 256 + threadIdx.x;  // float4 index
    if (i >= NN * (HH / 4)) return;
    int q = i & 31;
    float4 v = ((const float4*)y)[i];
    float4 A = ((const float4*)cA)[q];
    float4 B = ((const float4*)cB)[q];
    ushort4 o;
    o.x = f2b(gelu_exact(v.x * A.x + B.x));
    o.y = f2b(gelu_exact(v.y * A.y + B.y));
    o.z = f2b(gelu_exact(v.z * A.z + B.z));
    o.w = f2b(gelu_exact(v.w * A.w + B.w));
    ((ushort4*)hB)[i] = o;
}

// ---------------------------------------------------------------------------
// Head layer 3: dot-32 + sigmoid, 8 nodes/block
// ---------------------------------------------------------------------------
__global__ __launch_bounds__(256) void k_head3(const float* __restrict__ z2,
        const float* __restrict__ W3, const float* __restrict__ b3,
        float* __restrict__ out) {
    int tid = threadIdx.x;
    int k = tid & 31;
    int n = blockIdx.x * 8 + (tid >> 5);
    float w = W3[k];
    float v = (n < NN) ? z2[(size_t)n * 128 + k] * w : 0.0f;
    #pragma unroll
    for (int off = 16; off; off >>= 1) v += __shfl_xor(v, off, 32);
    if (k == 0 && n < NN) out[n] = 1.0f / (1.0f + expf(-(v + b3[0])));
}

// ---------------------------------------------------------------------------
// Launch
// ---------------------------------------------------------------------------
extern "C" void kernel_launch(void* const* d_in, const int* in_sizes, int n_in,
                              void* d_out, int out_size, void* d_ws, size_t ws_size,
                              hipStream_t stream) {
    const float* x   = (const float*)d_in[0];
    const int*   ei  = (const int*)d_in[1];
    const float* Wl0 = (const float*)d_in[2];
    const float* bl0 = (const float*)d_in[3];
    const float* Wr0 = (const float*)d_in[4];
    const float* gw0 = (const float*)d_in[5];
    const float* gb0 = (const float*)d_in[6];
    const float* ga0 = (const float*)d_in[7];
    const float* Wl1 = (const float*)d_in[8];
    const float* bl1 = (const float*)d_in[9];
    const float* Wr1 = (const float*)d_in[10];
    const float* gw1 = (const float*)d_in[11];
    const float* gb1 = (const float*)d_in[12];
    const float* ga1 = (const float*)d_in[13];
    const float* Wl2 = (const float*)d_in[14];
    const float* bl2 = (const float*)d_in[15];
    const float* Wr2 = (const float*)d_in[16];
    const float* gw2 = (const float*)d_in[17];
    const float* gb2 = (const float*)d_in[18];
    const float* ga2 = (const float*)d_in[19];
    const float* hW1 = (const float*)d_in[20];
    const float* hb1 = (const float*)d_in[21];
    const float* hW2 = (const float*)d_in[22];
    const float* hb2 = (const float*)d_in[23];
    const float* hW3 = (const float*)d_in[24];
    const float* hb3 = (const float*)d_in[25];
    float* out = (float*)d_out;

    size_t off = 0;
    auto carve = [&](size_t bytes) -> void* {
        void* p = (void*)((char*)d_ws + off);
        off += (bytes + 255) & ~(size_t)255;
        return p;
    };
    int*   deg       = (int*)carve((size_t)2 * NN * sizeof(int));
    int*   cnt       = deg + NN;
    int*   incl      = (int*)carve((size_t)NN * 4);
    int*   row_start = (int*)carve((size_t)NN * 4);
    float* invdeg    = (float*)carve((size_t)NN * 4);
    int*   bsum      = (int*)carve(512 * 4);
    int*   colarr    = (int*)carve((size_t)EE * 4);
    unsigned short* Wt2   = (unsigned short*)carve(128 * 256 * 2);
    unsigned short* WtH1  = (unsigned short*)carve(128 * 128 * 2);
    unsigned short* WtH2  = (unsigned short*)carve(128 * 64 * 2);
    float* biasH1    = (float*)carve(128 * 4);
    float* biasH2    = (float*)carve(128 * 4);
    float* ps        = (float*)carve(GNB * 128 * 4);
    float* pq        = (float*)carve(GNB * 128 * 4);
    float* coefA     = (float*)carve(128 * 4);
    float* coefB     = (float*)carve(128 * 4);
    float* agg0      = (float*)carve((size_t)NN * FIN * 4);
    float* bufB      = (float*)carve((size_t)NN * HH * 4);     // fp32 pre-norm y / z2
    unsigned short* hB   = (unsigned short*)carve((size_t)NN * HH * 2);
    unsigned short* aggB = (unsigned short*)carve((size_t)NN * HH * 2); // also z1b
    if (off > ws_size) return;

    const int* src = ei;
    const int* dst = ei + EE;
    const int MMB = (NN + 127) / 128;  // 782

    // CSR build
    hipMemsetAsync(deg, 0, (size_t)2 * NN * sizeof(int), stream);
    k_hist<<<(EE + 255) / 256, 256, 0, stream>>>(dst, deg);
    k_scan1<<<NB1, 256, 0, stream>>>(deg, incl, bsum);
    k_scan2<<<1, 512, 0, stream>>>(bsum);
    k_scan3<<<NB1, 256, 0, stream>>>(deg, incl, bsum, row_start, invdeg);
    k_scatter<<<(EE + 255) / 256, 256, 0, stream>>>(src, dst, row_start, cnt, colarr);

    // Layer 0 (fp32 vector)
    k_agg0<<<(NN + 3) / 4, 128, 0, stream>>>(x, row_start, deg, invdeg, colarr, agg0);
    k_l0<<<2048, 128, 0, stream>>>(agg0, x, Wl0, bl0, Wr0, bufB);
    k_gn_part<<<GNB, 256, 0, stream>>>(bufB, ps, pq);
    k_gn_final<<<1, 128, 0, stream>>>(ps, pq, gw0, gb0, ga0, coefA, coefB);
    k_gn_apply<<<(NN * (HH / 4) + 255) / 256, 256, 0, stream>>>(bufB, coefA, coefB, hB);

    // Layers 1 and 2 (bf16 MFMA)
    const float* WlL[2] = {Wl1, Wl2};
    const float* blL[2] = {bl1, bl2};
    const float* WrL[2] = {Wr1, Wr2};
    const float* gwL[2] = {gw1, gw2};
    const float* gbL[2] = {gb1, gb2};
    const float* gaL[2] = {ga1, ga2};
    for (int l = 0; l < 2; ++l) {
        k_pack_main<<<128, 256, 0, stream>>>(WlL[l], WrL[l], Wt2);
        k_aggb<<<NN, 64, 0, stream>>>(hB, row_start, deg, invdeg, colarr, aggB);
        k_mm<<<MMB, 256, 0, stream>>>(aggB, hB, 4, 8, 128, Wt2, 256, blL[l],
                                      bufB, (unsigned short*)nullptr, 0, NN);
        k_gn_part<<<GNB, 256, 0, stream>>>(bufB, ps, pq);
        k_gn_final<<<1, 128, 0, stream>>>(ps, pq, gwL[l], gbL[l], gaL[l], coefA, coefB);
        k_gn_apply<<<(NN * (HH / 4) + 255) / 256, 256, 0, stream>>>(bufB, coefA, coefB, hB);
    }

    // Head (bf16 MFMA for layers 1-2, padded to 128 cols; fp32 finale)
    k_pack_h1<<<64, 256, 0, stream>>>(hW1, WtH1);
    k_pack_h2<<<32, 256, 0, stream>>>(hW2, WtH2);
    k_padbias<<<1, 128, 0, stream>>>(hb1, 64, biasH1);
    k_padbias<<<1, 128, 0, stream>>>(hb2, 32, biasH2);
    // z1 = gelu(h @ W1^T + b1), bf16 out -> reuse aggB
    k_mm<<<MMB, 256, 0, stream>>>(hB, hB, 4, 4, 128, WtH1, 128, biasH1,
                                  (float*)nullptr, aggB, 1, NN);
    // z2 = gelu(z1 @ W2^T + b2), fp32 out -> reuse bufB
    k_mm<<<MMB, 256, 0, stream>>>(aggB, aggB, 2, 2, 128, WtH2, 64, biasH2,
                                  bufB, (unsigned short*)nullptr, 1, NN);
    k_head3<<<(NN + 7) / 8, 256, 0, stream>>>(bufB, hW3, hb3, out);
}

// Round 3
// 781.804 us; speedup vs baseline: 1.5580x; 1.1542x over previous
//
#include <hip/hip_runtime.h>
#include <hip/hip_bf16.h>
#include <math.h>

// Problem constants
#define NN 100000
#define EE 1600000
#define FIN 20
#define HH 128
#define GNB 256          // graphnorm partial blocks
#define NBUK 391         // ceil(NN/256) buckets of 256 nodes
#define FILLB 196        // ceil(EE/8192) fill blocks

typedef __attribute__((ext_vector_type(8))) short bf16x8;
typedef __attribute__((ext_vector_type(4))) float f32x4;

// bf16 helpers (RNE pack, cheap unpack)
__device__ __forceinline__ unsigned short f2b(float x) {
    unsigned int b = __float_as_uint(x);
    unsigned int r = b + 0x7fffu + ((b >> 16) & 1u);
    return (unsigned short)(r >> 16);
}
__device__ __forceinline__ float lof(unsigned int u) { return __uint_as_float(u << 16); }
__device__ __forceinline__ float hif(unsigned int u) { return __uint_as_float(u & 0xffff0000u); }

__device__ __forceinline__ float gelu_exact(float z) {
    return 0.5f * z * (1.0f + erff(z * 0.70710678118654752f));
}

// ---------------------------------------------------------------------------
// CSR build via bucketed binning (no random full-line HBM writes)
// ---------------------------------------------------------------------------
__global__ __launch_bounds__(256) void kb_cnt(const int* __restrict__ dst,
                                              int* __restrict__ bcnt) {
    __shared__ int c[NBUK];
    int t = threadIdx.x;
    for (int i = t; i < NBUK; i += 256) c[i] = 0;
    __syncthreads();
    int e0 = blockIdx.x * 8192;
    #pragma unroll 4
    for (int i = 0; i < 32; ++i) {
        int e = e0 + i * 256 + t;
        if (e < EE) atomicAdd(&c[dst[e] >> 8], 1);
    }
    __syncthreads();
    for (int i = t; i < NBUK; i += 256) if (c[i]) atomicAdd(&bcnt[i], c[i]);
}

__global__ void kb_scan(const int* __restrict__ bcnt, int* __restrict__ bbase,
                        int* __restrict__ cursor) {
    __shared__ int sh[512];
    int t = threadIdx.x;
    int v = (t < NBUK) ? bcnt[t] : 0;
    sh[t] = v;
    __syncthreads();
    for (int off = 1; off < 512; off <<= 1) {
        int add = (t >= off) ? sh[t - off] : 0;
        __syncthreads();
        sh[t] += add;
        __syncthreads();
    }
    if (t < NBUK) {
        int ex = sh[t] - v;
        bbase[t] = ex;
        cursor[t] = ex;
    }
    if (t == NBUK - 1) bbase[NBUK] = sh[t];
}

__global__ __launch_bounds__(256) void kb_fill(const int* __restrict__ src,
        const int* __restrict__ dst, int* __restrict__ cursor,
        unsigned int* __restrict__ pairs) {
    __shared__ int cnt[NBUK], base[NBUK], boff[NBUK];
    int t = threadIdx.x;
    for (int i = t; i < NBUK; i += 256) { cnt[i] = 0; boff[i] = 0; }
    __syncthreads();
    int e0 = blockIdx.x * 8192;
    #pragma unroll 4
    for (int i = 0; i < 32; ++i) {
        int e = e0 + i * 256 + t;
        if (e < EE) atomicAdd(&cnt[dst[e] >> 8], 1);
    }
    __syncthreads();
    for (int i = t; i < NBUK; i += 256)
        if (cnt[i]) base[i] = atomicAdd(&cursor[i], cnt[i]);
    __syncthreads();
    #pragma unroll 4
    for (int i = 0; i < 32; ++i) {
        int e = e0 + i * 256 + t;
        if (e < EE) {
            int d = dst[e];
            int b = d >> 8;
            int pos = base[b] + atomicAdd(&boff[b], 1);
            pairs[pos] = (unsigned int)src[e] | ((unsigned int)(d & 255) << 17);
        }
    }
}

__global__ __launch_bounds__(256) void kb_csr(const unsigned int* __restrict__ pairs,
        const int* __restrict__ bbase, int* __restrict__ row_start,
        int* __restrict__ deg, float* __restrict__ invdeg, int* __restrict__ col) {
    __shared__ int ldeg[256];
    __shared__ int lcnt[256];
    int b = blockIdx.x, t = threadIdx.x;
    int e0 = bbase[b], e1 = bbase[b + 1];
    ldeg[t] = 0;
    lcnt[t] = 0;
    __syncthreads();
    for (int e = e0 + t; e < e1; e += 256) atomicAdd(&ldeg[pairs[e] >> 17], 1);
    __syncthreads();
    int d = ldeg[t];
    // inclusive scan over ldeg (Hillis-Steele)
    for (int off = 1; off < 256; off <<= 1) {
        int add = (t >= off) ? ldeg[t - off] : 0;
        __syncthreads();
        ldeg[t] += add;
        __syncthreads();
    }
    int n = b * 256 + t;
    if (n < NN) {
        row_start[n] = e0 + ldeg[t] - d;
        deg[n] = d;
        invdeg[n] = 1.0f / fmaxf((float)d, 1.0f);
    }
    __syncthreads();
    for (int e = e0 + t; e < e1; e += 256) {
        unsigned int p = pairs[e];
        int dL = p >> 17;
        int pos = e0 + (dL ? ldeg[dL - 1] : 0) + atomicAdd(&lcnt[dL], 1);
        col[pos] = (int)(p & 0x1FFFFu);
    }
}

// ---------------------------------------------------------------------------
// Layer 0 (fp32): aggregate 20-wide x, fused dual GEMM K=20 with regs
// ---------------------------------------------------------------------------
__global__ void k_agg0(const float* __restrict__ x, const int* __restrict__ rs,
                       const int* __restrict__ deg, const float* __restrict__ inv,
                       const int* __restrict__ col, float* __restrict__ agg0) {
    int g = threadIdx.x >> 5;
    int l = threadIdx.x & 31;
    int n = blockIdx.x * 4 + g;
    if (n >= NN || l >= FIN) return;
    int s = rs[n], d = deg[n];
    float acc = 0.0f;
    int j = 0;
    for (; j + 1 < d; j += 2) {
        int c0 = col[s + j], c1 = col[s + j + 1];
        acc += x[c0 * FIN + l] + x[c1 * FIN + l];
    }
    if (j < d) acc += x[col[s + j] * FIN + l];
    agg0[n * FIN + l] = acc * inv[n];
}

__global__ __launch_bounds__(128) void k_l0(const float* __restrict__ agg0,
        const float* __restrict__ x, const float* __restrict__ Wl,
        const float* __restrict__ bl, const float* __restrict__ Wr,
        float* __restrict__ y) {
    int c = threadIdx.x;
    float wl[FIN], wr[FIN];
    #pragma unroll
    for (int k = 0; k < FIN; ++k) wl[k] = Wl[c * FIN + k];
    #pragma unroll
    for (int k = 0; k < FIN; ++k) wr[k] = Wr[c * FIN + k];
    float bc = bl[c];
    for (int n = blockIdx.x; n < NN; n += gridDim.x) {
        const float* ar = agg0 + (size_t)n * FIN;
        const float* xr = x + (size_t)n * FIN;
        float acc = bc;
        #pragma unroll
        for (int k = 0; k < FIN; ++k) acc = fmaf(ar[k], wl[k], acc);
        #pragma unroll
        for (int k = 0; k < FIN; ++k) acc = fmaf(xr[k], wr[k], acc);
        y[(size_t)n * HH + c] = acc;
    }
}

// ---------------------------------------------------------------------------
// bf16 aggregation: 1 wave per node, lane = 2 channels, coalesced 256 B rows
// ---------------------------------------------------------------------------
__global__ __launch_bounds__(64) void k_aggb(const unsigned short* __restrict__ hB,
        const int* __restrict__ rs, const int* __restrict__ deg,
        const float* __restrict__ inv, const int* __restrict__ col,
        unsigned short* __restrict__ aggB) {
    int n = blockIdx.x;
    int t = threadIdx.x;
    int s = rs[n], d = deg[n];
    const unsigned int* h32 = (const unsigned int*)hB;
    float a0 = 0.0f, a1 = 0.0f;
    int j = 0;
    for (; j + 3 < d; j += 4) {
        int c0 = col[s + j], c1 = col[s + j + 1];
        int c2 = col[s + j + 2], c3 = col[s + j + 3];
        unsigned int u0 = h32[(size_t)c0 * 64 + t];
        unsigned int u1 = h32[(size_t)c1 * 64 + t];
        unsigned int u2 = h32[(size_t)c2 * 64 + t];
        unsigned int u3 = h32[(size_t)c3 * 64 + t];
        a0 += lof(u0) + lof(u1) + lof(u2) + lof(u3);
        a1 += hif(u0) + hif(u1) + hif(u2) + hif(u3);
    }
    for (; j < d; ++j) {
        unsigned int u = h32[(size_t)col[s + j] * 64 + t];
        a0 += lof(u);
        a1 += hif(u);
    }
    float iv = inv[n];
    unsigned int o = (unsigned int)f2b(a0 * iv) | ((unsigned int)f2b(a1 * iv) << 16);
    ((unsigned int*)aggB)[(size_t)n * 64 + t] = o;
}

// ---------------------------------------------------------------------------
// Weight / bias packing to bf16 (B stored c-major: B[c][k])
// ---------------------------------------------------------------------------
__global__ void k_pack_main(const float* __restrict__ Wl, const float* __restrict__ Wr,
                            unsigned short* __restrict__ Wt) {
    int id = blockIdx.x * 256 + threadIdx.x;   // 32768
    int c = id >> 8, k = id & 255;
    float v = (k < HH) ? Wl[c * HH + k] : Wr[c * HH + (k - HH)];
    Wt[id] = f2b(v);
}

__global__ void k_pack_h1(const float* __restrict__ W, unsigned short* __restrict__ Wt) {
    int id = blockIdx.x * 256 + threadIdx.x;   // 128*128
    int c = id >> 7, k = id & 127;
    Wt[id] = f2b((c < 64) ? W[c * 128 + k] : 0.0f);
}

__global__ void k_pack_h2(const float* __restrict__ W, unsigned short* __restrict__ Wt) {
    int id = blockIdx.x * 256 + threadIdx.x;   // 128*64
    int c = id >> 6, k = id & 63;
    Wt[id] = f2b((c < 32) ? W[c * 64 + k] : 0.0f);
}

__global__ void k_padbias(const float* __restrict__ src, int n, float* __restrict__ dst) {
    int t = threadIdx.x;  // 128
    dst[t] = (t < n) ? src[t] : 0.0f;
}

// ---------------------------------------------------------------------------
// Generic bf16 MFMA GEMM: out[m][c] = act( sum_k A[m][k]*B[c][k] + bias[c] )
// ---------------------------------------------------------------------------
__global__ __launch_bounds__(256) void k_mm(const unsigned short* __restrict__ A0,
        const unsigned short* __restrict__ A1, int c0, int kChunks, int lda,
        const unsigned short* __restrict__ B, int ldb,
        const float* __restrict__ bias, float* outF, unsigned short* outB,
        int act, int M) {
    __shared__ __align__(16) unsigned short As[128 * 40];
    __shared__ __align__(16) unsigned short Bs[128 * 40];
    const int tid = threadIdx.x;
    const int m0 = blockIdx.x * 128;
    const int w = tid >> 6, lane = tid & 63;
    const int wr = w >> 1, wc = w & 1;
    const int m16 = lane & 15, q = lane >> 4;

    f32x4 acc[4][4];
    #pragma unroll
    for (int i = 0; i < 4; ++i)
        #pragma unroll
        for (int j = 0; j < 4; ++j) acc[i][j] = (f32x4){0.f, 0.f, 0.f, 0.f};

    for (int chunk = 0; chunk < kChunks; ++chunk) {
        const unsigned short* A = (chunk < c0) ? A0 : A1;
        const int kb = (chunk - ((chunk < c0) ? 0 : c0)) * 32;
        #pragma unroll
        for (int it = 0; it < 2; ++it) {
            int s = tid + it * 256;
            int r = s >> 2, p = s & 3;
            int gm = m0 + r;
            uint4 v = make_uint4(0u, 0u, 0u, 0u);
            if (gm < M) v = *(const uint4*)(A + (size_t)gm * lda + kb + p * 8);
            *(uint4*)&As[r * 40 + p * 8] = v;
        }
        {
            const int kbB = chunk * 32;
            #pragma unroll
            for (int it = 0; it < 2; ++it) {
                int s = tid + it * 256;
                int r = s >> 2, p = s & 3;
                uint4 v = *(const uint4*)(B + (size_t)r * ldb + kbB + p * 8);
                *(uint4*)&Bs[r * 40 + p * 8] = v;
            }
        }
        __syncthreads();
        bf16x8 af[4], bfr[4];
        #pragma unroll
        for (int i = 0; i < 4; ++i)
            af[i] = *(const bf16x8*)&As[(wr * 64 + i * 16 + m16) * 40 + q * 8];
        #pragma unroll
        for (int j = 0; j < 4; ++j)
            bfr[j] = *(const bf16x8*)&Bs[(wc * 64 + j * 16 + m16) * 40 + q * 8];
        #pragma unroll
        for (int i = 0; i < 4; ++i)
            #pragma unroll
            for (int j = 0; j < 4; ++j)
                acc[i][j] = __builtin_amdgcn_mfma_f32_16x16x32_bf16(af[i], bfr[j], acc[i][j], 0, 0, 0);
        __syncthreads();
    }

    #pragma unroll
    for (int i = 0; i < 4; ++i) {
        int mBase = m0 + wr * 64 + i * 16 + q * 4;
        #pragma unroll
        for (int j = 0; j < 4; ++j) {
            int cc = wc * 64 + j * 16 + m16;
            float bv = bias[cc];
            #pragma unroll
            for (int r = 0; r < 4; ++r) {
                int m = mBase + r;
                if (m < M) {
                    float v = acc[i][j][r] + bv;
                    if (act) v = gelu_exact(v);
                    if (outF) outF[(size_t)m * 128 + cc] = v;
                    if (outB) outB[(size_t)m * 128 + cc] = f2b(v);
                }
            }
        }
    }
}

// ---------------------------------------------------------------------------
// GraphNorm: partial sums, final coeffs, fused affine+GELU apply -> bf16
// ---------------------------------------------------------------------------
__global__ __launch_bounds__(256) void k_gn_part(const float* __restrict__ y,
        float* __restrict__ ps, float* __restrict__ pq) {
    int c = threadIdx.x & 127, half = threadIdx.x >> 7;
    float s = 0.0f, q = 0.0f;
    for (int n = blockIdx.x * 2 + half; n < NN; n += gridDim.x * 2) {
        float v = y[(size_t)n * HH + c];
        s += v;
        q += v * v;
    }
    __shared__ float sh[256], qh[256];
    sh[threadIdx.x] = s;
    qh[threadIdx.x] = q;
    __syncthreads();
    if (threadIdx.x < 128) {
        ps[blockIdx.x * 128 + c] = sh[c] + sh[c + 128];
        pq[blockIdx.x * 128 + c] = qh[c] + qh[c + 128];
    }
}

__global__ void k_gn_final(const float* __restrict__ ps, const float* __restrict__ pq,
                           const float* __restrict__ gw, const float* __restrict__ gb,
                           const float* __restrict__ ga, float* __restrict__ cA,
                           float* __restrict__ cB) {
    int c = threadIdx.x;  // 128
    double s = 0.0, q = 0.0;
    for (int b = 0; b < GNB; ++b) {
        s += (double)ps[b * 128 + c];
        q += (double)pq[b * 128 + c];
    }
    float mean = (float)(s / (double)NN);
    float msq  = (float)(q / (double)NN);
    float a = ga[c];
    float var = msq - mean * mean * a * (2.0f - a);
    float rstd = rsqrtf(var + 1e-5f);
    float A = gw[c] * rstd;
    cA[c] = A;
    cB[c] = gb[c] - a * mean * A;
}

__global__ __launch_bounds__(256) void k_gn_apply(const float* __restrict__ y,
        const float* __restrict__ cA, const float* __restrict__ cB,
        unsigned short* __restrict__ hB) {
    int i = blockIdx.x * 256 + threadIdx.x;  // float4 index
    if (i >= NN * (HH / 4)) return;
    int q = i & 31;
    float4 v = ((const float4*)y)[i];
    float4 A = ((const float4*)cA)[q];
    float4 B = ((const float4*)cB)[q];
    ushort4 o;
    o.x = f2b(gelu_exact(v.x * A.x + B.x));
    o.y = f2b(gelu_exact(v.y * A.y + B.y));
    o.z = f2b(gelu_exact(v.z * A.z + B.z));
    o.w = f2b(gelu_exact(v.w * A.w + B.w));
    ((ushort4*)hB)[i] = o;
}

// ---------------------------------------------------------------------------
// Head layer 3: dot-32 + sigmoid, 8 nodes/block
// ---------------------------------------------------------------------------
__global__ __launch_bounds__(256) void k_head3(const float* __restrict__ z2,
        const float* __restrict__ W3, const float* __restrict__ b3,
        float* __restrict__ out) {
    int tid = threadIdx.x;
    int k = tid & 31;
    int n = blockIdx.x * 8 + (tid >> 5);
    float w = W3[k];
    float v = (n < NN) ? z2[(size_t)n * 128 + k] * w : 0.0f;
    #pragma unroll
    for (int off = 16; off; off >>= 1) v += __shfl_xor(v, off, 32);
    if (k == 0 && n < NN) out[n] = 1.0f / (1.0f + expf(-(v + b3[0])));
}

// ---------------------------------------------------------------------------
// Launch
// ---------------------------------------------------------------------------
extern "C" void kernel_launch(void* const* d_in, const int* in_sizes, int n_in,
                              void* d_out, int out_size, void* d_ws, size_t ws_size,
                              hipStream_t stream) {
    const float* x   = (const float*)d_in[0];
    const int*   ei  = (const int*)d_in[1];
    const float* Wl0 = (const float*)d_in[2];
    const float* bl0 = (const float*)d_in[3];
    const float* Wr0 = (const float*)d_in[4];
    const float* gw0 = (const float*)d_in[5];
    const float* gb0 = (const float*)d_in[6];
    const float* ga0 = (const float*)d_in[7];
    const float* Wl1 = (const float*)d_in[8];
    const float* bl1 = (const float*)d_in[9];
    const float* Wr1 = (const float*)d_in[10];
    const float* gw1 = (const float*)d_in[11];
    const float* gb1 = (const float*)d_in[12];
    const float* ga1 = (const float*)d_in[13];
    const float* Wl2 = (const float*)d_in[14];
    const float* bl2 = (const float*)d_in[15];
    const float* Wr2 = (const float*)d_in[16];
    const float* gw2 = (const float*)d_in[17];
    const float* gb2 = (const float*)d_in[18];
    const float* ga2 = (const float*)d_in[19];
    const float* hW1 = (const float*)d_in[20];
    const float* hb1 = (const float*)d_in[21];
    const float* hW2 = (const float*)d_in[22];
    const float* hb2 = (const float*)d_in[23];
    const float* hW3 = (const float*)d_in[24];
    const float* hb3 = (const float*)d_in[25];
    float* out = (float*)d_out;

    size_t off = 0;
    auto carve = [&](size_t bytes) -> void* {
        void* p = (void*)((char*)d_ws + off);
        off += (bytes + 255) & ~(size_t)255;
        return p;
    };
    int*   bcnt      = (int*)carve((size_t)NBUK * 4);
    int*   bbase     = (int*)carve((size_t)(NBUK + 1) * 4);
    int*   cursor    = (int*)carve((size_t)NBUK * 4);
    unsigned int* pairs = (unsigned int*)carve((size_t)EE * 4);
    int*   deg       = (int*)carve((size_t)NN * 4);
    int*   row_start = (int*)carve((size_t)NN * 4);
    float* invdeg    = (float*)carve((size_t)NN * 4);
    int*   colarr    = (int*)carve((size_t)EE * 4);
    unsigned short* Wt2   = (unsigned short*)carve(128 * 256 * 2);
    unsigned short* WtH1  = (unsigned short*)carve(128 * 128 * 2);
    unsigned short* WtH2  = (unsigned short*)carve(128 * 64 * 2);
    float* biasH1    = (float*)carve(128 * 4);
    float* biasH2    = (float*)carve(128 * 4);
    float* ps        = (float*)carve(GNB * 128 * 4);
    float* pq        = (float*)carve(GNB * 128 * 4);
    float* coefA     = (float*)carve(128 * 4);
    float* coefB     = (float*)carve(128 * 4);
    float* agg0      = (float*)carve((size_t)NN * FIN * 4);
    float* bufB      = (float*)carve((size_t)NN * HH * 4);
    unsigned short* hB   = (unsigned short*)carve((size_t)NN * HH * 2);
    unsigned short* aggB = (unsigned short*)carve((size_t)NN * HH * 2);
    if (off > ws_size) return;

    const int* src = ei;
    const int* dst = ei + EE;
    const int MMB = (NN + 127) / 128;  // 782

    // CSR build (bucketed)
    hipMemsetAsync(bcnt, 0, (size_t)NBUK * 4, stream);
    kb_cnt<<<FILLB, 256, 0, stream>>>(dst, bcnt);
    kb_scan<<<1, 512, 0, stream>>>(bcnt, bbase, cursor);
    kb_fill<<<FILLB, 256, 0, stream>>>(src, dst, cursor, pairs);
    kb_csr<<<NBUK, 256, 0, stream>>>(pairs, bbase, row_start, deg, invdeg, colarr);

    // Layer 0 (fp32 vector)
    k_agg0<<<(NN + 3) / 4, 128, 0, stream>>>(x, row_start, deg, invdeg, colarr, agg0);
    k_l0<<<2048, 128, 0, stream>>>(agg0, x, Wl0, bl0, Wr0, bufB);
    k_gn_part<<<GNB, 256, 0, stream>>>(bufB, ps, pq);
    k_gn_final<<<1, 128, 0, stream>>>(ps, pq, gw0, gb0, ga0, coefA, coefB);
    k_gn_apply<<<(NN * (HH / 4) + 255) / 256, 256, 0, stream>>>(bufB, coefA, coefB, hB);

    // Layers 1 and 2 (bf16 MFMA)
    const float* WlL[2] = {Wl1, Wl2};
    const float* blL[2] = {bl1, bl2};
    const float* WrL[2] = {Wr1, Wr2};
    const float* gwL[2] = {gw1, gw2};
    const float* gbL[2] = {gb1, gb2};
    const float* gaL[2] = {ga1, ga2};
    for (int l = 0; l < 2; ++l) {
        k_pack_main<<<128, 256, 0, stream>>>(WlL[l], WrL[l], Wt2);
        k_aggb<<<NN, 64, 0, stream>>>(hB, row_start, deg, invdeg, colarr, aggB);
        k_mm<<<MMB, 256, 0, stream>>>(aggB, hB, 4, 8, 128, Wt2, 256, blL[l],
                                      bufB, (unsigned short*)nullptr, 0, NN);
        k_gn_part<<<GNB, 256, 0, stream>>>(bufB, ps, pq);
        k_gn_final<<<1, 128, 0, stream>>>(ps, pq, gwL[l], gbL[l], gaL[l], coefA, coefB);
        k_gn_apply<<<(NN * (HH / 4) + 255) / 256, 256, 0, stream>>>(bufB, coefA, coefB, hB);
    }

    // Head
    k_pack_h1<<<64, 256, 0, stream>>>(hW1, WtH1);
    k_pack_h2<<<32, 256, 0, stream>>>(hW2, WtH2);
    k_padbias<<<1, 128, 0, stream>>>(hb1, 64, biasH1);
    k_padbias<<<1, 128, 0, stream>>>(hb2, 32, biasH2);
    k_mm<<<MMB, 256, 0, stream>>>(hB, hB, 4, 4, 128, WtH1, 128, biasH1,
                                  (float*)nullptr, aggB, 1, NN);
    k_mm<<<MMB, 256, 0, stream>>>(aggB, aggB, 2, 2, 128, WtH2, 64, biasH2,
                                  bufB, (unsigned short*)nullptr, 1, NN);
    k_head3<<<(NN + 7) / 8, 256, 0, stream>>>(bufB, hW3, hb3, out);
}